// Round 8
// baseline (383.729 us; speedup 1.0000x reference)
//
#include <hip/hip_runtime.h>
#include <cstdint>
#include <cstddef>

typedef __attribute__((ext_vector_type(8))) __bf16 bf16x8;
typedef __attribute__((ext_vector_type(16))) float floatx16;

struct SrcPtrs { const float* p[9]; };

// ---------------- weight workspace layout (bf16 elems) ----------------
// Frag-major per layer: frag f = t*S + s (t = 32-feature tile, s = 16-k step).
// Each frag = 1024 B = 64 lanes x 16 B; lane l = q2*32 + l31 holds
// row (32t + l31), k = 16s + 8*q2 + {0..7} — exactly the 32x32x16 bf16
// A-operand layout. Serves BOTH paths: coalesced global_load_dwordx4 from L2
// and (after contiguous staging) conflict-free ds_read_b128 from LDS.
// m  mat    K    Nout  S   NT  off(shorts)  remap
// 0  Wd1_0  60   128   4   4   0
// 1  Wd1_1  128  128   8   4   8192
// 2  Wd1_2  128  128   8   4   24576
// 3  Wd2_0  188  128   12  4   40960    k<60 -> 128+k, k>=60 -> k-60
// 4  Wd2_1  128  128   8   4   65536
// 5  Wd2_2  128  128   8   4   81920
// 6  Wd2_3  128  129   8   5   98304    col0 -> row128 (blend), col j+1 -> row j
// 7  Wc_0   152  128   10  4   118784   k<24 -> 128+k, k>=24 -> k-24
// 8  Wc_1   128  3     8   1   139264   rows 3..31 zero
// total 143360 shorts = 286720 B

__global__ void prep_zero(unsigned short* __restrict__ ws) {
  uint4* p = (uint4*)ws;
  const int n = 143360 / 8;
  for (int i = blockIdx.x * blockDim.x + threadIdx.x; i < n; i += gridDim.x * blockDim.x)
    p[i] = make_uint4(0u, 0u, 0u, 0u);
}

__global__ void prep_fill(SrcPtrs sp, unsigned short* __restrict__ ws) {
  const int m  = blockIdx.x >> 4;
  const int sl = blockIdx.x & 15;
  const int K[9]  = {60, 128, 128, 188, 128, 128, 128, 152, 128};
  const int N[9]  = {128, 128, 128, 128, 128, 128, 129, 128, 3};
  const int SS[9] = {4, 8, 8, 12, 8, 8, 8, 10, 8};
  const unsigned OFF[9] = {0u, 8192u, 24576u, 40960u, 65536u, 81920u, 98304u, 118784u, 139264u};
  const int Km = K[m], Nm = N[m], Sm = SS[m];
  const float* __restrict__ src = sp.p[m];
  unsigned short* __restrict__ dst = ws + OFF[m];
  const int tot = Km * Nm;
  for (int i = sl * 256 + (int)threadIdx.x; i < tot; i += 16 * 256) {
    int k = i / Nm;
    int n = i - k * Nm;
    int kk = k, row = n;
    if (m == 3) kk = (k < 60) ? 128 + k : k - 60;
    if (m == 7) kk = (k < 24) ? 128 + k : k - 24;
    if (m == 6) row = (n == 0) ? 128 : n - 1;
    const int t = row >> 5, l31 = row & 31;
    const int s = kk >> 4, q2 = (kk >> 3) & 1, j = kk & 7;
    dst[(t * Sm + s) * 512 + (q2 * 32 + l31) * 8 + j] =
        __builtin_bit_cast(unsigned short, (__bf16)src[i]);
  }
}

// ---------------- main fused kernel ----------------

#if defined(__has_builtin)
#if __has_builtin(__builtin_amdgcn_permlane32_swap)
#define HAVE_PLSWAP 1
#endif
#endif
#ifndef HAVE_PLSWAP
#define HAVE_PLSWAP 0
#endif

__device__ __forceinline__ unsigned pk2(float a, float b) {
  unsigned short ua = __builtin_bit_cast(unsigned short, (__bf16)a);
  unsigned short ub = __builtin_bit_cast(unsigned short, (__bf16)b);
  return (unsigned)ua | ((unsigned)ub << 16);
}

__device__ __forceinline__ void stage16(const void* g, void* l) {
  __builtin_amdgcn_global_load_lds(
      (const __attribute__((address_space(1))) unsigned int*)g,
      (__attribute__((address_space(3))) unsigned int*)l, 16, 0, 0);
}

// lo = q2==0 ? own a : partner's b ; hi = q2==0 ? partner's a : own b
__device__ __forceinline__ void half_swap(unsigned a, unsigned b, int q2,
                                          unsigned& lo, unsigned& hi) {
#if HAVE_PLSWAP
  auto r = __builtin_amdgcn_permlane32_swap(a, b, false, false);
  lo = r[0]; hi = r[1];
#else
  unsigned sa = __shfl_xor(a, 32, 64);
  unsigned sb = __shfl_xor(b, 32, 64);
  lo = q2 ? sb : a;
  hi = q2 ? b : sa;
#endif
}

// sin/cos of v * pi * 2^f == sin/cos(2*pi*rev), rev = v * 2^(f-1) (HW revolutions)
// KIND 0: positional enc, k2 = 16*sl + 8*q2 + j: d=k2/20, f=(k2%20)>>1, valid k2<60
// KIND 1: view enc: d=3+k2/8, f=(k2%8)>>1, valid k2<24
template <int KIND>
__device__ __forceinline__ bf16x8 trig_frag(const float (&x)[6], int q2, int sl) {
  bf16x8 r;
#pragma unroll
  for (int j = 0; j < 8; ++j) {
    const int kA = 16 * sl + j;       // q2 == 0
    const int kB = 16 * sl + 8 + j;   // q2 == 1
    int dA, dB; float scA, scB; bool vA, vB;
    if (KIND == 0) {
      vA = kA < 60; vB = kB < 60;
      dA = kA / 20; dB = kB / 20;
      scA = (float)(1 << ((kA % 20) >> 1)) * 0.5f;
      scB = (float)(1 << ((kB % 20) >> 1)) * 0.5f;
    } else {
      vA = kA < 24; vB = kB < 24;
      dA = 3 + (kA >> 3); dB = 3 + (kB >> 3);
      scA = (float)(1 << ((kA & 7) >> 1)) * 0.5f;
      scB = (float)(1 << ((kB & 7) >> 1)) * 0.5f;
    }
    float v  = q2 ? x[dB] : x[dA];
    float sc = q2 ? scB : scA;
    bool ok  = q2 ? vB : vA;
    float rev = v * sc;
    float t = (j & 1) ? __builtin_amdgcn_cosf(rev) : __builtin_amdgcn_sinf(rev);
    r[j] = (__bf16)(ok ? t : 0.0f);
  }
  return r;
}

// 32x32x16 bf16 MFMA, A = weights (m=feature), B = activations (n=point).
// ONE m-tile (32 points) per wave -> minimal register state (~112/wave incl
// acc) -> 4 waves/SIMD. Activations flow register-to-register: the epilogue
// converts C-layout acc directly into the NEXT layer's B-frags (half_swap),
// so no pkv array and no LDS for activations.
// A sourcing is frag-granular hybrid: frag f = t*S+s < HF comes from the
// 24 KB LDS ping-pong buffer (staged one layer ahead, 1 barrier/layer);
// f >= HF streams from L2 (all 8 waves read the same lines -> L1 hits).
// OUTM: 0=bfout, 1=d2_3 (bfout feats + density/blend), 2=c_1 (rgb).
template <int S, int SL, int ST, int KIND, int NT, int HF, int PP, bool RELU, int OUTM>
__device__ __forceinline__ void run_layer(const unsigned short* __restrict__ wsrc,
                                          const unsigned short* __restrict__ nsrc, int nbytes,
                                          unsigned short* __restrict__ sWt,
                                          const bf16x8 (&bfin)[8], bf16x8 (&bfout)[8],
                                          const float (&x)[6],
                                          float* __restrict__ out, int base, int tid) {
  const int lane = tid & 63;
  const int w = tid >> 6;
  const int q2 = lane >> 5;
  const int l31 = lane & 31;
  const int pt = base + w * 32 + l31;

  __syncthreads();  // buf[PP] staged (issued a full layer ago, drained here);
                    // buf[PP^1] free (its readers finished last layer)

  // stage NEXT layer's LDS-half into buf[PP^1] (drains at the NEXT barrier)
  if (nbytes > 0) {
    const uint4* __restrict__ s4 = (const uint4*)nsrc;
    uint4* __restrict__ dst = (uint4*)(sWt + (PP ^ 1) * 12288);
    const int n16 = nbytes / 16;
    for (int i = tid; i < n16; i += 512)
      stage16(s4 + i, dst + (i & ~63));
  }

  // trig tail B-frags (VALU; overlaps staging)
  bf16x8 tail[ST > 0 ? ST : 1];
#pragma unroll
  for (int j = 0; j < ST; ++j) tail[j] = trig_frag<KIND>(x, q2, j);

  const unsigned short* __restrict__ ldsbuf = sWt + PP * 12288;
  const uint4* __restrict__ wp = (const uint4*)wsrc;
#pragma unroll
  for (int t = 0; t < NT; ++t) {
    floatx16 acc;
#pragma unroll
    for (int i = 0; i < 16; ++i) acc[i] = 0.0f;
#pragma unroll
    for (int s = 0; s < S; ++s) {
      constexpr int dummy = 0; (void)dummy;
      const int f = t * S + s;  // compile-time per unrolled iter
      bf16x8 A;
      if (f < HF) {
        A = *(const bf16x8*)&ldsbuf[f * 512 + lane * 8];
      } else {
        uint4 a4 = wp[f * 64 + lane];
        A = __builtin_bit_cast(bf16x8, a4);
      }
      bf16x8 B = (s < SL) ? bfin[(s < SL) ? s : 0] : tail[s - SL];
      acc = __builtin_amdgcn_mfma_f32_32x32x16_bf16(A, B, acc, 0, 0, 0);
    }
    if (OUTM == 2) {
      if (q2 == 0) {  // rgb = rows 0..2 -> regs 0..2 at q2==0
        float* o = out + (size_t)pt * 5;
        o[0] = acc[0]; o[1] = acc[1]; o[2] = acc[2];
      }
    } else {
      if (OUTM == 0 || t < 4) {
        // epilogue-direct B-frag build: frag s' = 2t+h from local groups 2h, 2h+1
#pragma unroll
        for (int h = 0; h < 2; ++h) {
          float a0 = acc[8 * h + 0], a1 = acc[8 * h + 1];
          float a2 = acc[8 * h + 2], a3 = acc[8 * h + 3];
          float b0 = acc[8 * h + 4], b1 = acc[8 * h + 5];
          float b2 = acc[8 * h + 6], b3 = acc[8 * h + 7];
          if (RELU) {
            a0 = fmaxf(a0, 0.f); a1 = fmaxf(a1, 0.f);
            a2 = fmaxf(a2, 0.f); a3 = fmaxf(a3, 0.f);
            b0 = fmaxf(b0, 0.f); b1 = fmaxf(b1, 0.f);
            b2 = fmaxf(b2, 0.f); b3 = fmaxf(b3, 0.f);
          }
          unsigned p0x = pk2(a0, a1), p0y = pk2(a2, a3);
          unsigned p1x = pk2(b0, b1), p1y = pk2(b2, b3);
          unsigned w0, w1, w2, w3;
          half_swap(p0x, p1x, q2, w0, w2);
          half_swap(p0y, p1y, q2, w1, w3);
          bfout[2 * t + h] = __builtin_bit_cast(bf16x8, make_uint4(w0, w1, w2, w3));
        }
      }
      if (OUTM == 1 && q2 == 0) {
        if (t == 0) out[(size_t)pt * 5 + 3] = acc[0];  // density = feature[:,0]
        if (t == 4)                                     // blending = sigmoid(row 128)
          out[(size_t)pt * 5 + 4] = 1.0f / (1.0f + __expf(-acc[0]));
      }
    }
  }
}

__global__ __launch_bounds__(512, 4) void nerf_main(const float* __restrict__ x,
                                                    const unsigned short* __restrict__ ws,
                                                    float* __restrict__ out) {
  __shared__ __align__(16) unsigned short sWt[2 * 12288];  // 2 x 24 KB ping-pong

  const int tid = (int)threadIdx.x;
  const int base = (int)blockIdx.x * 256;
  const int lane = tid & 63;
  const int w = tid >> 6;
  const int q2 = lane >> 5;
  const int l31 = lane & 31;
  const int pt = base + w * 32 + l31;

  // stage layer 0 (16 KB, all frags) into buf0 immediately
  {
    const uint4* s4 = (const uint4*)ws;
    uint4* dst = (uint4*)sWt;
#pragma unroll
    for (int i = 0; i < 2; ++i)
      stage16(s4 + i * 512 + tid, dst + ((i * 512 + tid) & ~63));
  }

  // per-lane x in registers (pt fixed per lane for whole kernel)
  float x6[6];
  {
    const float* a = x + (size_t)pt * 6;
#pragma unroll
    for (int c = 0; c < 3; ++c) {
      float2 u = *(const float2*)(a + 2 * c);
      x6[2 * c] = u.x; x6[2 * c + 1] = u.y;
    }
  }

  bf16x8 F1[8], F2[8];

  //          S   SL ST K  NT  HF PP relu  out           wsrc          next_src      next_bytes
  run_layer< 4, 0, 4, 0, 4, 16, 0, true , 0>(ws + 0u,      ws + 8192u,   24576, sWt, F2, F1, x6, out, base, tid); // d1_0 (B=enc_pos)
  run_layer< 8, 8, 0, 0, 4, 24, 1, true , 0>(ws + 8192u,   ws + 24576u,  24576, sWt, F1, F2, x6, out, base, tid); // d1_1
  run_layer< 8, 8, 0, 0, 4, 24, 0, false, 0>(ws + 24576u,  ws + 40960u,  24576, sWt, F2, F1, x6, out, base, tid); // d1_2 -> part1
  run_layer<12, 8, 4, 0, 4, 24, 1, true , 0>(ws + 40960u,  ws + 65536u,  24576, sWt, F1, F2, x6, out, base, tid); // d2_0 [part1|enc_pos]
  run_layer< 8, 8, 0, 0, 4, 24, 0, true , 0>(ws + 65536u,  ws + 81920u,  24576, sWt, F2, F1, x6, out, base, tid); // d2_1
  run_layer< 8, 8, 0, 0, 4, 24, 1, true , 0>(ws + 81920u,  ws + 98304u,  24576, sWt, F1, F2, x6, out, base, tid); // d2_2
  run_layer< 8, 8, 0, 0, 5, 24, 0, false, 1>(ws + 98304u,  ws + 118784u, 24576, sWt, F2, F1, x6, out, base, tid); // d2_3 -> feat,dens,blend
  run_layer<10, 8, 2, 1, 4, 24, 1, true , 0>(ws + 118784u, ws + 139264u,  8192, sWt, F1, F2, x6, out, base, tid); // c_0 [feature|enc_view]
  run_layer< 8, 8, 0, 0, 1,  8, 0, false, 2>(ws + 139264u, (const unsigned short*)nullptr, 0, sWt, F2, F1, x6, out, base, tid); // c_1 -> rgb
}

extern "C" void kernel_launch(void* const* d_in, const int* in_sizes, int n_in,
                              void* d_out, int out_size, void* d_ws, size_t ws_size,
                              hipStream_t stream) {
  (void)n_in; (void)out_size; (void)ws_size;
  const float* x = (const float*)d_in[0];
  SrcPtrs sp;
  for (int i = 0; i < 9; ++i) sp.p[i] = (const float*)d_in[1 + i];
  unsigned short* ws = (unsigned short*)d_ws;
  float* out = (float*)d_out;
  const int N = in_sizes[0] / 6;

  prep_zero<<<70, 256, 0, stream>>>(ws);
  prep_fill<<<144, 256, 0, stream>>>(sp, ws);
  nerf_main<<<N / 256, 512, 0, stream>>>(x, ws, out);
}